// Round 13
// baseline (279.442 us; speedup 1.0000x reference)
//
#include <hip/hip_runtime.h>
#include <hip/hip_fp16.h>

// ---------------------------------------------------------------------------
// PMLP forward: 3 x (GEMM -> symmetric-norm propagate -> bias[+relu])
// N=50000 nodes, E=800000 edges, dims 128->128->128->64, fp32 in/out.
// R2: scatter -> CSR gather.  R3: GEMM LDS swizzle.  R4: 4-edge unroll.
// R5 REVERTED: src sort.      R6: atomic-free CSR; fp16 P.
// R7: flat fill; NB=256.      R8: hierarchical scan. R9: fp16 MFMA GEMM.
// R10: u8 CSR metadata; edata 4B/edge.
// R11: k_gemm0 inline fp32->fp16 convert (kept).
// R12 REVERTED: fused gather+GEMM. Post-mortem: block-granular barrier
//      couples 8 waves to the slowest of 64 nodes with only 3 blocks/CU to
//      fill the bubble -> gather streams at 1.47 TB/s vs 2.6 unfused.
//      Fusion saved ~5us of H traffic but cost ~10us/layer. Unfuse.
// R13: separate barrier-free gather (3125 blocks) + gemm; gather MLP
//      deepened to 8 concurrent P loads; A/B fp16 ping-pong buffers.
// ---------------------------------------------------------------------------

#define NB 256          // histogram blocks / sort chunks (E/NB = 3125)
#define NBINS 50000
#define HW4 12500       // LDS words, 4 u8 bins per word

typedef unsigned int uint32;
typedef unsigned char uint8;
typedef _Float16 half8 __attribute__((ext_vector_type(8)));
typedef float floatx4 __attribute__((ext_vector_type(4)));

// ---------------- converts ----------------
__global__ __launch_bounds__(256) void k_cvtw(const float* __restrict__ w0,
                                              const float* __restrict__ w1,
                                              const float* __restrict__ w2,
                                              __half* __restrict__ dst) {
    int i = blockIdx.x * 256 + threadIdx.x;   // quad index, 0..10239
    if (i >= 10240) return;
    const float* s;
    int off;
    if (i < 4096)      { s = w0; off = i; }
    else if (i < 8192) { s = w1; off = i - 4096; }
    else               { s = w2; off = i - 8192; }
    float4 v = reinterpret_cast<const float4*>(s)[off];
    __half2 h0 = __floats2half2_rn(v.x, v.y);
    __half2 h1 = __floats2half2_rn(v.z, v.w);
    uint2 o;
    o.x = *reinterpret_cast<uint32*>(&h0);
    o.y = *reinterpret_cast<uint32*>(&h1);
    reinterpret_cast<uint2*>(dst)[i] = o;
}

// ---------------- CSR build (atomic-free, u8 metadata) ----------------
__global__ __launch_bounds__(256) void k_hist(const int* __restrict__ ei,
                                              uint8* __restrict__ rank,
                                              uint32* __restrict__ partial, int E) {
    __shared__ uint32 h[HW4];   // 50 KB
    const int b = blockIdx.x;
    const int chunk = (E + NB - 1) / NB;
    const int base = b * chunk;
    const int lim = min(base + chunk, E);
    for (int w = threadIdx.x; w < HW4; w += 256) h[w] = 0;
    __syncthreads();
    for (int e = base + threadIdx.x; e < lim; e += 256) {
        int c = ei[E + e];
        int sh = (c & 3) * 8;
        uint32 old = atomicAdd(&h[c >> 2], 1u << sh);
        rank[e] = (uint8)((old >> sh) & 0xffu);
    }
    __syncthreads();
    uint32* dst = partial + (size_t)b * HW4;
    for (int w = threadIdx.x; w < HW4; w += 256) dst[w] = h[w];
}

__global__ __launch_bounds__(256) void k_merge(const uint32* __restrict__ partial,
                                               uint32* __restrict__ bp,
                                               int* __restrict__ bsum,
                                               int* __restrict__ offs,
                                               float* __restrict__ dinv, int n) {
    __shared__ int wsums[5];
    const int tid = threadIdx.x;
    const int bin = blockIdx.x * 256 + tid;
    const int lane = tid & 63;
    const int wid = tid >> 6;
    uint32 run = 0;
    if (bin < n) {
        const int word = bin >> 2;
        const int sh = (bin & 3) * 8;
        uint32* dst = bp + (size_t)bin * (NB / 4);
#pragma unroll 4
        for (int b = 0; b < NB; b += 4) {
            uint32 c0 = (partial[(size_t)(b + 0) * HW4 + word] >> sh) & 0xffu;
            uint32 c1 = (partial[(size_t)(b + 1) * HW4 + word] >> sh) & 0xffu;
            uint32 c2 = (partial[(size_t)(b + 2) * HW4 + word] >> sh) & 0xffu;
            uint32 c3 = (partial[(size_t)(b + 3) * HW4 + word] >> sh) & 0xffu;
            uint32 p1 = run + c0, p2 = p1 + c1, p3 = p2 + c2;
            dst[b >> 2] = run | (p1 << 8) | (p2 << 16) | (p3 << 24);
            run = p3 + c3;
        }
        dinv[bin] = rsqrtf((float)run + 1.0f);
    }
    int s = (int)run;
#pragma unroll
    for (int off = 1; off < 64; off <<= 1) {
        int t = __shfl_up(s, off);
        if (lane >= off) s += t;
    }
    if (lane == 63) wsums[wid] = s;
    __syncthreads();
    if (tid == 0) {
        int a = 0;
        for (int w = 0; w < 4; ++w) { int t = wsums[w]; wsums[w] = a; a += t; }
        wsums[4] = a;
    }
    __syncthreads();
    if (bin < n) offs[bin] = wsums[wid] + s - (int)run;
    if (tid == 255) bsum[blockIdx.x] = wsums[4];
}

__global__ __launch_bounds__(256) void k_scan_top(const int* __restrict__ bsum,
                                                  int* __restrict__ bpre,
                                                  int* __restrict__ offs,
                                                  int nblk, int n) {
    __shared__ int wsums[5];
    const int tid = threadIdx.x;
    const int lane = tid & 63;
    const int wid = tid >> 6;
    int v = (tid < nblk) ? bsum[tid] : 0;
    int s = v;
#pragma unroll
    for (int off = 1; off < 64; off <<= 1) {
        int t = __shfl_up(s, off);
        if (lane >= off) s += t;
    }
    if (lane == 63) wsums[wid] = s;
    __syncthreads();
    if (tid == 0) {
        int a = 0;
        for (int w = 0; w < 4; ++w) { int t = wsums[w]; wsums[w] = a; a += t; }
        wsums[4] = a;
    }
    __syncthreads();
    if (tid < nblk) bpre[tid] = wsums[wid] + s - v;
    if (tid == 0) offs[n] = wsums[4];
}

__global__ __launch_bounds__(256) void k_add(int* __restrict__ offs,
                                             const int* __restrict__ bpre, int n) {
    int bin = blockIdx.x * 256 + threadIdx.x;
    if (bin < n) offs[bin] += bpre[blockIdx.x];
}

__global__ __launch_bounds__(256) void k_fill(const int* __restrict__ ei,
                                              const int* __restrict__ offs,
                                              const uint32* __restrict__ bp,
                                              const uint8* __restrict__ rank,
                                              const float* __restrict__ dinv,
                                              uint32* __restrict__ edata, int E) {
    int e = blockIdx.x * 256 + threadIdx.x;
    if (e >= E) return;
    const int chunk = (E + NB - 1) / NB;
    int b = e / chunk;
    int r = ei[e];
    int c = ei[E + e];
    uint32 pk = bp[(size_t)c * (NB / 4) + (b >> 2)];
    int pref = (pk >> ((b & 3) * 8)) & 0xff;
    int pos = offs[c] + pref + (int)rank[e];
    __half h = __float2half(dinv[r] * dinv[c]);
    unsigned short hb = *reinterpret_cast<unsigned short*>(&h);
    edata[pos] = (uint32)(unsigned short)r | ((uint32)hb << 16);
}

// ---------------- gather helpers ----------------
struct f8 { float4 lo, hi; };
__device__ inline f8 cvt8(uint4 u) {
    __half2* h = reinterpret_cast<__half2*>(&u);
    float2 a = __half22float2(h[0]);
    float2 b = __half22float2(h[1]);
    float2 c = __half22float2(h[2]);
    float2 d = __half22float2(h[3]);
    f8 r;
    r.lo = make_float4(a.x, a.y, b.x, b.y);
    r.hi = make_float4(c.x, c.y, d.x, d.y);
    return r;
}
__device__ inline void fma8(f8& acc, float s, const f8& v) {
    acc.lo.x += s * v.lo.x; acc.lo.y += s * v.lo.y;
    acc.lo.z += s * v.lo.z; acc.lo.w += s * v.lo.w;
    acc.hi.x += s * v.hi.x; acc.hi.y += s * v.hi.y;
    acc.hi.z += s * v.hi.z; acc.hi.w += s * v.hi.w;
}
__device__ inline float nrm16(uint32 ed) {
    unsigned short u = (unsigned short)(ed >> 16);
    __half h;
    __builtin_memcpy(&h, &u, 2);
    return __half2float(h);
}

// H[dst][:] = relu?( dinv[dst]^2 * P[dst][:] + sum norm * P[row][:] + bias )
// LANES lanes/node, 8 halves per lane. 8-deep MLP main loop, then 4, then 1.
template <int LANES, bool RELU, bool OUTH>
__global__ __launch_bounds__(256) void k_gather(const __half* __restrict__ P,
                                                const int* __restrict__ offs,
                                                const uint32* __restrict__ edata,
                                                const float* __restrict__ dinv,
                                                const float* __restrict__ bias,
                                                void* __restrict__ Hout, int n) {
    int t = blockIdx.x * 256 + threadIdx.x;
    int node = t / LANES;
    int c = t % LANES;
    if (node >= n) return;
    const uint4* Pv = reinterpret_cast<const uint4*>(P);

    float s = dinv[node];
    s *= s;
    f8 acc = cvt8(Pv[(size_t)node * LANES + c]);
    acc.lo.x *= s; acc.lo.y *= s; acc.lo.z *= s; acc.lo.w *= s;
    acc.hi.x *= s; acc.hi.y *= s; acc.hi.z *= s; acc.hi.w *= s;
    f8 acc2 = {make_float4(0, 0, 0, 0), make_float4(0, 0, 0, 0)};

    int j = offs[node];
    const int end = offs[node + 1];
    for (; j + 8 <= end; j += 8) {
        uint32 e0 = edata[j + 0];
        uint32 e1 = edata[j + 1];
        uint32 e2 = edata[j + 2];
        uint32 e3 = edata[j + 3];
        uint32 e4 = edata[j + 4];
        uint32 e5 = edata[j + 5];
        uint32 e6 = edata[j + 6];
        uint32 e7 = edata[j + 7];
        uint4 u0 = Pv[(size_t)(e0 & 0xffffu) * LANES + c];
        uint4 u1 = Pv[(size_t)(e1 & 0xffffu) * LANES + c];
        uint4 u2 = Pv[(size_t)(e2 & 0xffffu) * LANES + c];
        uint4 u3 = Pv[(size_t)(e3 & 0xffffu) * LANES + c];
        uint4 u4 = Pv[(size_t)(e4 & 0xffffu) * LANES + c];
        uint4 u5 = Pv[(size_t)(e5 & 0xffffu) * LANES + c];
        uint4 u6 = Pv[(size_t)(e6 & 0xffffu) * LANES + c];
        uint4 u7 = Pv[(size_t)(e7 & 0xffffu) * LANES + c];
        fma8(acc,  nrm16(e0), cvt8(u0));
        fma8(acc2, nrm16(e1), cvt8(u1));
        fma8(acc,  nrm16(e2), cvt8(u2));
        fma8(acc2, nrm16(e3), cvt8(u3));
        fma8(acc,  nrm16(e4), cvt8(u4));
        fma8(acc2, nrm16(e5), cvt8(u5));
        fma8(acc,  nrm16(e6), cvt8(u6));
        fma8(acc2, nrm16(e7), cvt8(u7));
    }
    if (j + 4 <= end) {
        uint32 e0 = edata[j + 0];
        uint32 e1 = edata[j + 1];
        uint32 e2 = edata[j + 2];
        uint32 e3 = edata[j + 3];
        uint4 u0 = Pv[(size_t)(e0 & 0xffffu) * LANES + c];
        uint4 u1 = Pv[(size_t)(e1 & 0xffffu) * LANES + c];
        uint4 u2 = Pv[(size_t)(e2 & 0xffffu) * LANES + c];
        uint4 u3 = Pv[(size_t)(e3 & 0xffffu) * LANES + c];
        fma8(acc,  nrm16(e0), cvt8(u0));
        fma8(acc2, nrm16(e1), cvt8(u1));
        fma8(acc,  nrm16(e2), cvt8(u2));
        fma8(acc2, nrm16(e3), cvt8(u3));
        j += 4;
    }
    for (; j < end; ++j) {
        uint32 ed = edata[j];
        fma8(acc, nrm16(ed), cvt8(Pv[(size_t)(ed & 0xffffu) * LANES + c]));
    }
    const float4* bv = reinterpret_cast<const float4*>(bias);
    float4 b0 = bv[c * 2], b1 = bv[c * 2 + 1];
    acc.lo.x += acc2.lo.x + b0.x; acc.lo.y += acc2.lo.y + b0.y;
    acc.lo.z += acc2.lo.z + b0.z; acc.lo.w += acc2.lo.w + b0.w;
    acc.hi.x += acc2.hi.x + b1.x; acc.hi.y += acc2.hi.y + b1.y;
    acc.hi.z += acc2.hi.z + b1.z; acc.hi.w += acc2.hi.w + b1.w;
    if (RELU) {
        acc.lo.x = fmaxf(acc.lo.x, 0.f); acc.lo.y = fmaxf(acc.lo.y, 0.f);
        acc.lo.z = fmaxf(acc.lo.z, 0.f); acc.lo.w = fmaxf(acc.lo.w, 0.f);
        acc.hi.x = fmaxf(acc.hi.x, 0.f); acc.hi.y = fmaxf(acc.hi.y, 0.f);
        acc.hi.z = fmaxf(acc.hi.z, 0.f); acc.hi.w = fmaxf(acc.hi.w, 0.f);
    }
    if (OUTH) {
        __half2 h0 = __floats2half2_rn(acc.lo.x, acc.lo.y);
        __half2 h1 = __floats2half2_rn(acc.lo.z, acc.lo.w);
        __half2 h2 = __floats2half2_rn(acc.hi.x, acc.hi.y);
        __half2 h3 = __floats2half2_rn(acc.hi.z, acc.hi.w);
        uint4 o;
        o.x = *reinterpret_cast<uint32*>(&h0);
        o.y = *reinterpret_cast<uint32*>(&h1);
        o.z = *reinterpret_cast<uint32*>(&h2);
        o.w = *reinterpret_cast<uint32*>(&h3);
        reinterpret_cast<uint4*>(Hout)[(size_t)node * LANES + c] = o;
    } else {
        float4* H = reinterpret_cast<float4*>(Hout);
        H[(size_t)node * LANES * 2 + c * 2] = acc.lo;
        H[(size_t)node * LANES * 2 + c * 2 + 1] = acc.hi;
    }
}

// ---------------- layer-0 GEMM: P0[m][n] = sum_k x_f32[m][k] W[n][k] -------
template <int NT>
__global__ __launch_bounds__(256) void k_gemm0(const float* __restrict__ A,
                                               const __half* __restrict__ W,
                                               __half* __restrict__ C, int M) {
    const int N = NT * 16;
    const int tid = threadIdx.x;
    const int wave = tid >> 6;
    const int lane = tid & 63;
    const int lm = lane & 15;
    const int quad = lane >> 4;
    const int row = blockIdx.x * 64 + wave * 16 + lm;
    const bool av = row < M;

    floatx4 acc[NT] = {};
#pragma unroll
    for (int kc = 0; kc < 4; ++kc) {
        const int kk = kc * 32 + quad * 8;
        half8 a = {};
        if (av) {
            float4 f0 = *reinterpret_cast<const float4*>(A + (size_t)row * 128 + kk);
            float4 f1 = *reinterpret_cast<const float4*>(A + (size_t)row * 128 + kk + 4);
            a[0] = (_Float16)f0.x; a[1] = (_Float16)f0.y;
            a[2] = (_Float16)f0.z; a[3] = (_Float16)f0.w;
            a[4] = (_Float16)f1.x; a[5] = (_Float16)f1.y;
            a[6] = (_Float16)f1.z; a[7] = (_Float16)f1.w;
        }
#pragma unroll
        for (int ct = 0; ct < NT; ++ct) {
            half8 b = *reinterpret_cast<const half8*>(W + (size_t)(ct * 16 + lm) * 128 + kk);
            acc[ct] = __builtin_amdgcn_mfma_f32_16x16x32_f16(a, b, acc[ct], 0, 0, 0);
        }
    }
    const int rbase = blockIdx.x * 64 + wave * 16 + quad * 4;
#pragma unroll
    for (int reg = 0; reg < 4; ++reg) {
        int r = rbase + reg;
        if (r < M) {
#pragma unroll
            for (int ct = 0; ct < NT; ++ct)
                C[(size_t)r * N + ct * 16 + lm] = __float2half(acc[ct][reg]);
        }
    }
}

// ---------------- fp16 GEMM: C[m][n] = sum_k A[m][k] W[n][k] ---------------
template <int NT>
__global__ __launch_bounds__(256) void k_gemm16(const __half* __restrict__ A,
                                                const __half* __restrict__ W,
                                                __half* __restrict__ C, int M) {
    const int N = NT * 16;
    const int tid = threadIdx.x;
    const int wave = tid >> 6;
    const int lane = tid & 63;
    const int lm = lane & 15;
    const int quad = lane >> 4;
    const int row = blockIdx.x * 64 + wave * 16 + lm;
    const bool av = row < M;

    floatx4 acc[NT] = {};
#pragma unroll
    for (int kc = 0; kc < 4; ++kc) {
        const int kk = kc * 32 + quad * 8;
        half8 a = {};
        if (av) a = *reinterpret_cast<const half8*>(A + (size_t)row * 128 + kk);
#pragma unroll
        for (int ct = 0; ct < NT; ++ct) {
            half8 b = *reinterpret_cast<const half8*>(W + (size_t)(ct * 16 + lm) * 128 + kk);
            acc[ct] = __builtin_amdgcn_mfma_f32_16x16x32_f16(a, b, acc[ct], 0, 0, 0);
        }
    }
    const int rbase = blockIdx.x * 64 + wave * 16 + quad * 4;
#pragma unroll
    for (int reg = 0; reg < 4; ++reg) {
        int r = rbase + reg;
        if (r < M) {
#pragma unroll
            for (int ct = 0; ct < NT; ++ct)
                C[(size_t)r * N + ct * 16 + lm] = __float2half(acc[ct][reg]);
        }
    }
}

extern "C" void kernel_launch(void* const* d_in, const int* in_sizes, int n_in,
                              void* d_out, int out_size, void* d_ws, size_t ws_size,
                              hipStream_t stream) {
    const float* x  = (const float*)d_in[0];
    const int*   ei = (const int*)d_in[1];   // [2][E] int32
    const float* W0 = (const float*)d_in[2];
    const float* b0 = (const float*)d_in[3];
    const float* W1 = (const float*)d_in[4];
    const float* b1 = (const float*)d_in[5];
    const float* W2 = (const float*)d_in[6];
    const float* b2 = (const float*)d_in[7];
    float* out = (float*)d_out;

    const int n = in_sizes[0] / 128;   // 50000
    const int E = in_sizes[1] / 2;     // 800000
    const int NBLK = (n + 255) / 256;  // 196

    // workspace (~43 MB):
    // bp(12.8M u8x4) rank(0.8M) bsum/bpre offs dinv edata(3.2M)
    // A fp16(12.8M) B fp16(12.8M) Wh(80K)
    // partial (12.8M) ALIASES A (dead until gemm0).
    // Ping-pong: gemm0 x->A, gather A->B, gemm B->A, gather A->B,
    //            gemm B->A(64), gather A->out.
    const int S = 51200;
    uint32* bp    = (uint32*)d_ws;
    uint8*  rank  = (uint8*)(bp + (size_t)NBINS * (NB / 4));
    int*    bsum  = (int*)(rank + E);
    int*    bpre  = bsum + 256;
    int*    offs  = bsum + S;
    float*  dinv  = (float*)(offs + S);
    uint32* edata = (uint32*)(dinv + S);
    __half* A     = (__half*)(edata + E);
    __half* B     = A + (size_t)n * 128;
    __half* Wh    = B + (size_t)n * 128;
    uint32* partial = (uint32*)A;   // NB*HW4 u32 = 12.8M = sizeof(A)

    // ---- one-time weight convert
    k_cvtw<<<40, 256, 0, stream>>>(W0, W1, W2, Wh);

    // ---- CSR build, zero global atomics
    k_hist<<<NB, 256, 0, stream>>>(ei, rank, partial, E);
    k_merge<<<NBLK, 256, 0, stream>>>(partial, bp, bsum, offs, dinv, n);
    k_scan_top<<<1, 256, 0, stream>>>(bsum, bpre, offs, NBLK, n);
    k_add<<<NBLK, 256, 0, stream>>>(offs, bpre, n);
    k_fill<<<(E + 255) / 256, 256, 0, stream>>>(ei, offs, bp, rank, dinv, edata, E);

    const int blocks64 = (n + 63) / 64;           // 782
    const int gB128 = (n * 16 + 255) / 256;       // 3125 (LANES=16)
    const int gB64  = (n * 8 + 255) / 256;        // 1563 (LANES=8)

    // ---- Layer 0
    k_gemm0<8><<<blocks64, 256, 0, stream>>>(x, Wh, A, n);
    k_gather<16, true, true><<<gB128, 256, 0, stream>>>(
        A, offs, edata, dinv, b0, B, n);
    // ---- Layer 1
    k_gemm16<8><<<blocks64, 256, 0, stream>>>(B, Wh + 16384, A, n);
    k_gather<16, true, true><<<gB128, 256, 0, stream>>>(
        A, offs, edata, dinv, b1, B, n);
    // ---- Layer 2 (N=64, fp32 out, no relu)
    k_gemm16<4><<<blocks64, 256, 0, stream>>>(B, Wh + 32768, A, n);
    k_gather<8, false, false><<<gB64, 256, 0, stream>>>(
        A, offs, edata, dinv, b2, out, n);
}

// Round 14
// 254.743 us; speedup vs baseline: 1.0970x; 1.0970x over previous
//
#include <hip/hip_runtime.h>
#include <hip/hip_fp16.h>

// ---------------------------------------------------------------------------
// PMLP forward: 3 x (GEMM -> symmetric-norm propagate -> bias[+relu])
// N=50000 nodes, E=800000 edges, dims 128->128->128->64, fp32 in/out.
// R2: scatter -> CSR gather.  R3: GEMM LDS swizzle.  R4: 4-edge unroll.
// R5 REVERTED: src sort.      R6: atomic-free CSR; fp16 P.
// R7: flat fill; NB=256.      R8: hierarchical scan. R9: fp16 MFMA GEMM.
// R10: u8 CSR metadata.       R11: fused gather+GEMM (best so far, 264.6us).
// R12/R13 measured: fused-512 270.6, unfused 279.4 -> fusion saves ~15us,
//      its only cost is the block-barrier straggler at low blocks/CU.
// R14: barrier-FREE fusion: 128-thread blocks, 2 autonomous waves; each wave
//      gathers its own 16 nodes into its own 4KB LDS slice then MFMAs those
//      16 rows immediately (wave-internal LDS ordering, no __syncthreads).
//      1563 blocks, no cross-wave coupling.
// ---------------------------------------------------------------------------

#define NB 256          // histogram blocks / sort chunks (E/NB = 3125)
#define NBINS 50000
#define HW4 12500       // LDS words, 4 u8 bins per word

typedef unsigned int uint32;
typedef unsigned char uint8;
typedef _Float16 half8 __attribute__((ext_vector_type(8)));
typedef float floatx4 __attribute__((ext_vector_type(4)));

// ---------------- converts ----------------
__global__ __launch_bounds__(256) void k_cvtw(const float* __restrict__ w0,
                                              const float* __restrict__ w1,
                                              const float* __restrict__ w2,
                                              __half* __restrict__ dst) {
    int i = blockIdx.x * 256 + threadIdx.x;   // quad index, 0..10239
    if (i >= 10240) return;
    const float* s;
    int off;
    if (i < 4096)      { s = w0; off = i; }
    else if (i < 8192) { s = w1; off = i - 4096; }
    else               { s = w2; off = i - 8192; }
    float4 v = reinterpret_cast<const float4*>(s)[off];
    __half2 h0 = __floats2half2_rn(v.x, v.y);
    __half2 h1 = __floats2half2_rn(v.z, v.w);
    uint2 o;
    o.x = *reinterpret_cast<uint32*>(&h0);
    o.y = *reinterpret_cast<uint32*>(&h1);
    reinterpret_cast<uint2*>(dst)[i] = o;
}

// ---------------- CSR build (atomic-free, u8 metadata) ----------------
__global__ __launch_bounds__(256) void k_hist(const int* __restrict__ ei,
                                              uint8* __restrict__ rank,
                                              uint32* __restrict__ partial, int E) {
    __shared__ uint32 h[HW4];   // 50 KB
    const int b = blockIdx.x;
    const int chunk = (E + NB - 1) / NB;
    const int base = b * chunk;
    const int lim = min(base + chunk, E);
    for (int w = threadIdx.x; w < HW4; w += 256) h[w] = 0;
    __syncthreads();
    for (int e = base + threadIdx.x; e < lim; e += 256) {
        int c = ei[E + e];
        int sh = (c & 3) * 8;
        uint32 old = atomicAdd(&h[c >> 2], 1u << sh);
        rank[e] = (uint8)((old >> sh) & 0xffu);
    }
    __syncthreads();
    uint32* dst = partial + (size_t)b * HW4;
    for (int w = threadIdx.x; w < HW4; w += 256) dst[w] = h[w];
}

__global__ __launch_bounds__(256) void k_merge(const uint32* __restrict__ partial,
                                               uint32* __restrict__ bp,
                                               int* __restrict__ bsum,
                                               int* __restrict__ offs,
                                               float* __restrict__ dinv, int n) {
    __shared__ int wsums[5];
    const int tid = threadIdx.x;
    const int bin = blockIdx.x * 256 + tid;
    const int lane = tid & 63;
    const int wid = tid >> 6;
    uint32 run = 0;
    if (bin < n) {
        const int word = bin >> 2;
        const int sh = (bin & 3) * 8;
        uint32* dst = bp + (size_t)bin * (NB / 4);
#pragma unroll 4
        for (int b = 0; b < NB; b += 4) {
            uint32 c0 = (partial[(size_t)(b + 0) * HW4 + word] >> sh) & 0xffu;
            uint32 c1 = (partial[(size_t)(b + 1) * HW4 + word] >> sh) & 0xffu;
            uint32 c2 = (partial[(size_t)(b + 2) * HW4 + word] >> sh) & 0xffu;
            uint32 c3 = (partial[(size_t)(b + 3) * HW4 + word] >> sh) & 0xffu;
            uint32 p1 = run + c0, p2 = p1 + c1, p3 = p2 + c2;
            dst[b >> 2] = run | (p1 << 8) | (p2 << 16) | (p3 << 24);
            run = p3 + c3;
        }
        dinv[bin] = rsqrtf((float)run + 1.0f);
    }
    int s = (int)run;
#pragma unroll
    for (int off = 1; off < 64; off <<= 1) {
        int t = __shfl_up(s, off);
        if (lane >= off) s += t;
    }
    if (lane == 63) wsums[wid] = s;
    __syncthreads();
    if (tid == 0) {
        int a = 0;
        for (int w = 0; w < 4; ++w) { int t = wsums[w]; wsums[w] = a; a += t; }
        wsums[4] = a;
    }
    __syncthreads();
    if (bin < n) offs[bin] = wsums[wid] + s - (int)run;
    if (tid == 255) bsum[blockIdx.x] = wsums[4];
}

__global__ __launch_bounds__(256) void k_scan_top(const int* __restrict__ bsum,
                                                  int* __restrict__ bpre,
                                                  int* __restrict__ offs,
                                                  int nblk, int n) {
    __shared__ int wsums[5];
    const int tid = threadIdx.x;
    const int lane = tid & 63;
    const int wid = tid >> 6;
    int v = (tid < nblk) ? bsum[tid] : 0;
    int s = v;
#pragma unroll
    for (int off = 1; off < 64; off <<= 1) {
        int t = __shfl_up(s, off);
        if (lane >= off) s += t;
    }
    if (lane == 63) wsums[wid] = s;
    __syncthreads();
    if (tid == 0) {
        int a = 0;
        for (int w = 0; w < 4; ++w) { int t = wsums[w]; wsums[w] = a; a += t; }
        wsums[4] = a;
    }
    __syncthreads();
    if (tid < nblk) bpre[tid] = wsums[wid] + s - v;
    if (tid == 0) offs[n] = wsums[4];
}

__global__ __launch_bounds__(256) void k_add(int* __restrict__ offs,
                                             const int* __restrict__ bpre, int n) {
    int bin = blockIdx.x * 256 + threadIdx.x;
    if (bin < n) offs[bin] += bpre[blockIdx.x];
}

__global__ __launch_bounds__(256) void k_fill(const int* __restrict__ ei,
                                              const int* __restrict__ offs,
                                              const uint32* __restrict__ bp,
                                              const uint8* __restrict__ rank,
                                              const float* __restrict__ dinv,
                                              uint32* __restrict__ edata, int E) {
    int e = blockIdx.x * 256 + threadIdx.x;
    if (e >= E) return;
    const int chunk = (E + NB - 1) / NB;
    int b = e / chunk;
    int r = ei[e];
    int c = ei[E + e];
    uint32 pk = bp[(size_t)c * (NB / 4) + (b >> 2)];
    int pref = (pk >> ((b & 3) * 8)) & 0xff;
    int pos = offs[c] + pref + (int)rank[e];
    __half h = __float2half(dinv[r] * dinv[c]);
    unsigned short hb = *reinterpret_cast<unsigned short*>(&h);
    edata[pos] = (uint32)(unsigned short)r | ((uint32)hb << 16);
}

// ---------------- gather helpers ----------------
struct f8 { float4 lo, hi; };
__device__ inline f8 cvt8(uint4 u) {
    __half2* h = reinterpret_cast<__half2*>(&u);
    float2 a = __half22float2(h[0]);
    float2 b = __half22float2(h[1]);
    float2 c = __half22float2(h[2]);
    float2 d = __half22float2(h[3]);
    f8 r;
    r.lo = make_float4(a.x, a.y, b.x, b.y);
    r.hi = make_float4(c.x, c.y, d.x, d.y);
    return r;
}
__device__ inline void fma8(f8& acc, float s, const f8& v) {
    acc.lo.x += s * v.lo.x; acc.lo.y += s * v.lo.y;
    acc.lo.z += s * v.lo.z; acc.lo.w += s * v.lo.w;
    acc.hi.x += s * v.hi.x; acc.hi.y += s * v.hi.y;
    acc.hi.z += s * v.hi.z; acc.hi.w += s * v.hi.w;
}
__device__ inline float nrm16(uint32 ed) {
    unsigned short u = (unsigned short)(ed >> 16);
    __half h;
    __builtin_memcpy(&h, &u, 2);
    return __half2float(h);
}
// one node's 8-half chunk (c of 16): self + edges + bias, relu'd
__device__ inline f8 gather_node(const uint4* __restrict__ Pv,
                                 const int* __restrict__ offs,
                                 const uint32* __restrict__ edata,
                                 const float* __restrict__ dinv,
                                 const float* __restrict__ bias,
                                 int node, int c) {
    float s = dinv[node];
    s *= s;
    f8 acc = cvt8(Pv[(size_t)node * 16 + c]);
    acc.lo.x *= s; acc.lo.y *= s; acc.lo.z *= s; acc.lo.w *= s;
    acc.hi.x *= s; acc.hi.y *= s; acc.hi.z *= s; acc.hi.w *= s;
    f8 acc2 = {make_float4(0, 0, 0, 0), make_float4(0, 0, 0, 0)};
    int j = offs[node];
    const int end = offs[node + 1];
    for (; j + 4 <= end; j += 4) {
        uint32 e0 = edata[j + 0];
        uint32 e1 = edata[j + 1];
        uint32 e2 = edata[j + 2];
        uint32 e3 = edata[j + 3];
        uint4 u0 = Pv[(size_t)(e0 & 0xffffu) * 16 + c];
        uint4 u1 = Pv[(size_t)(e1 & 0xffffu) * 16 + c];
        uint4 u2 = Pv[(size_t)(e2 & 0xffffu) * 16 + c];
        uint4 u3 = Pv[(size_t)(e3 & 0xffffu) * 16 + c];
        fma8(acc,  nrm16(e0), cvt8(u0));
        fma8(acc2, nrm16(e1), cvt8(u1));
        fma8(acc,  nrm16(e2), cvt8(u2));
        fma8(acc2, nrm16(e3), cvt8(u3));
    }
    for (; j < end; ++j) {
        uint32 ed = edata[j];
        fma8(acc, nrm16(ed), cvt8(Pv[(size_t)(ed & 0xffffu) * 16 + c]));
    }
    const float4* bv = reinterpret_cast<const float4*>(bias);
    float4 b0 = bv[c * 2], b1 = bv[c * 2 + 1];
    acc.lo.x += acc2.lo.x + b0.x; acc.lo.y += acc2.lo.y + b0.y;
    acc.lo.z += acc2.lo.z + b0.z; acc.lo.w += acc2.lo.w + b0.w;
    acc.hi.x += acc2.hi.x + b1.x; acc.hi.y += acc2.hi.y + b1.y;
    acc.hi.z += acc2.hi.z + b1.z; acc.hi.w += acc2.hi.w + b1.w;
    acc.lo.x = fmaxf(acc.lo.x, 0.f); acc.lo.y = fmaxf(acc.lo.y, 0.f);
    acc.lo.z = fmaxf(acc.lo.z, 0.f); acc.lo.w = fmaxf(acc.lo.w, 0.f);
    acc.hi.x = fmaxf(acc.hi.x, 0.f); acc.hi.y = fmaxf(acc.hi.y, 0.f);
    acc.hi.z = fmaxf(acc.hi.z, 0.f); acc.hi.w = fmaxf(acc.hi.w, 0.f);
    return acc;
}
__device__ inline uint4 pack8(const f8& a) {
    __half2 h0 = __floats2half2_rn(a.lo.x, a.lo.y);
    __half2 h1 = __floats2half2_rn(a.lo.z, a.lo.w);
    __half2 h2 = __floats2half2_rn(a.hi.x, a.hi.y);
    __half2 h3 = __floats2half2_rn(a.hi.z, a.hi.w);
    uint4 o;
    o.x = *reinterpret_cast<uint32*>(&h0);
    o.y = *reinterpret_cast<uint32*>(&h1);
    o.z = *reinterpret_cast<uint32*>(&h2);
    o.w = *reinterpret_cast<uint32*>(&h3);
    return o;
}

// ---------------- layer-0 GEMM: P0[m][n] = sum_k x_f32[m][k] W[n][k] -------
template <int NT>
__global__ __launch_bounds__(256) void k_gemm0(const float* __restrict__ A,
                                               const __half* __restrict__ W,
                                               __half* __restrict__ C, int M) {
    const int N = NT * 16;
    const int tid = threadIdx.x;
    const int wave = tid >> 6;
    const int lane = tid & 63;
    const int lm = lane & 15;
    const int quad = lane >> 4;
    const int row = blockIdx.x * 64 + wave * 16 + lm;
    const bool av = row < M;

    floatx4 acc[NT] = {};
#pragma unroll
    for (int kc = 0; kc < 4; ++kc) {
        const int kk = kc * 32 + quad * 8;
        half8 a = {};
        if (av) {
            float4 f0 = *reinterpret_cast<const float4*>(A + (size_t)row * 128 + kk);
            float4 f1 = *reinterpret_cast<const float4*>(A + (size_t)row * 128 + kk + 4);
            a[0] = (_Float16)f0.x; a[1] = (_Float16)f0.y;
            a[2] = (_Float16)f0.z; a[3] = (_Float16)f0.w;
            a[4] = (_Float16)f1.x; a[5] = (_Float16)f1.y;
            a[6] = (_Float16)f1.z; a[7] = (_Float16)f1.w;
        }
#pragma unroll
        for (int ct = 0; ct < NT; ++ct) {
            half8 b = *reinterpret_cast<const half8*>(W + (size_t)(ct * 16 + lm) * 128 + kk);
            acc[ct] = __builtin_amdgcn_mfma_f32_16x16x32_f16(a, b, acc[ct], 0, 0, 0);
        }
    }
    const int rbase = blockIdx.x * 64 + wave * 16 + quad * 4;
#pragma unroll
    for (int reg = 0; reg < 4; ++reg) {
        int r = rbase + reg;
        if (r < M) {
#pragma unroll
            for (int ct = 0; ct < NT; ++ct)
                C[(size_t)r * N + ct * 16 + lm] = __float2half(acc[ct][reg]);
        }
    }
}

// ---------------- barrier-free fused gather+GEMM ---------------------------
// Block = 128 thr = 2 autonomous waves. Wave w: gather its 16 nodes into its
// own 4KB LDS slice (relu(gather(P)+bias), fp16, XOR-swizzled groups), then
// MFMA those 16 rows vs W (L2). NO __syncthreads — wave-internal LDS order.
template <int NT>
__global__ __launch_bounds__(128) void k_gg(const __half* __restrict__ P,
                                            const int* __restrict__ offs,
                                            const uint32* __restrict__ edata,
                                            const float* __restrict__ dinv,
                                            const float* __restrict__ bias,
                                            const __half* __restrict__ W,
                                            __half* __restrict__ C, int n) {
    __shared__ __align__(16) __half Hs[2][16 * 128];  // 8 KB, 4KB per wave
    const int N = NT * 16;
    const int tid = threadIdx.x;
    const int wave = tid >> 6;
    const int lane = tid & 63;
    const uint4* Pv = reinterpret_cast<const uint4*>(P);
    const int c = lane & 15;      // half-group 0..15 (8 halves each)
    const int u = lane >> 4;      // 0..3
    const int nbase = blockIdx.x * 32 + wave * 16;
    __half* hs = Hs[wave];

#pragma unroll 1
    for (int sub = 0; sub < 4; ++sub) {
        const int lrow = sub * 4 + u;
        const int node = nbase + lrow;
        f8 acc = {make_float4(0, 0, 0, 0), make_float4(0, 0, 0, 0)};
        if (node < n)
            acc = gather_node(Pv, offs, edata, dinv, bias, node, c);
        *reinterpret_cast<uint4*>(&hs[lrow * 128 + ((c ^ (lrow & 7)) << 3)]) =
            pack8(acc);
    }
    // no barrier: same wave wrote all 16 rows it reads below (lgkmcnt order)

    const int lm = lane & 15;
    const int quad = lane >> 4;
    floatx4 acc[NT] = {};
#pragma unroll
    for (int kc = 0; kc < 4; ++kc) {
        const int g = kc * 4 + quad;
        half8 a = *reinterpret_cast<const half8*>(
            &hs[lm * 128 + ((g ^ (lm & 7)) << 3)]);
        const int kk = g << 3;
#pragma unroll
        for (int ct = 0; ct < NT; ++ct) {
            half8 b = *reinterpret_cast<const half8*>(
                W + (size_t)(ct * 16 + lm) * 128 + kk);
            acc[ct] = __builtin_amdgcn_mfma_f32_16x16x32_f16(a, b, acc[ct], 0, 0, 0);
        }
    }
    const int rbase = nbase + quad * 4;
#pragma unroll
    for (int reg = 0; reg < 4; ++reg) {
        int r = rbase + reg;
        if (r < n) {
#pragma unroll
            for (int ct = 0; ct < NT; ++ct)
                C[(size_t)r * N + ct * 16 + lm] = __float2half(acc[ct][reg]);
        }
    }
}

// ---------------- final gather (D=64, fp32 out, no relu) -------------------
__global__ __launch_bounds__(256) void k_gather_out(const __half* __restrict__ P,
                                                    const int* __restrict__ offs,
                                                    const uint32* __restrict__ edata,
                                                    const float* __restrict__ dinv,
                                                    const float* __restrict__ bias,
                                                    float* __restrict__ out, int n) {
    const int LANES = 8;
    int t = blockIdx.x * 256 + threadIdx.x;
    int node = t / LANES;
    int c = t % LANES;
    if (node >= n) return;
    const uint4* Pv = reinterpret_cast<const uint4*>(P);

    float s = dinv[node];
    s *= s;
    f8 acc = cvt8(Pv[(size_t)node * LANES + c]);
    acc.lo.x *= s; acc.lo.y *= s; acc.lo.z *= s; acc.lo.w *= s;
    acc.hi.x *= s; acc.hi.y *= s; acc.hi.z *= s; acc.hi.w *= s;
    f8 acc2 = {make_float4(0, 0, 0, 0), make_float4(0, 0, 0, 0)};

    int j = offs[node];
    const int end = offs[node + 1];
    for (; j + 4 <= end; j += 4) {
        uint32 e0 = edata[j + 0];
        uint32 e1 = edata[j + 1];
        uint32 e2 = edata[j + 2];
        uint32 e3 = edata[j + 3];
        uint4 u0 = Pv[(size_t)(e0 & 0xffffu) * LANES + c];
        uint4 u1 = Pv[(size_t)(e1 & 0xffffu) * LANES + c];
        uint4 u2 = Pv[(size_t)(e2 & 0xffffu) * LANES + c];
        uint4 u3 = Pv[(size_t)(e3 & 0xffffu) * LANES + c];
        fma8(acc,  nrm16(e0), cvt8(u0));
        fma8(acc2, nrm16(e1), cvt8(u1));
        fma8(acc,  nrm16(e2), cvt8(u2));
        fma8(acc2, nrm16(e3), cvt8(u3));
    }
    for (; j < end; ++j) {
        uint32 ed = edata[j];
        fma8(acc, nrm16(ed), cvt8(Pv[(size_t)(ed & 0xffffu) * LANES + c]));
    }
    const float4* bv = reinterpret_cast<const float4*>(bias);
    float4 b0 = bv[c * 2], b1 = bv[c * 2 + 1];
    acc.lo.x += acc2.lo.x + b0.x; acc.lo.y += acc2.lo.y + b0.y;
    acc.lo.z += acc2.lo.z + b0.z; acc.lo.w += acc2.lo.w + b0.w;
    acc.hi.x += acc2.hi.x + b1.x; acc.hi.y += acc2.hi.y + b1.y;
    acc.hi.z += acc2.hi.z + b1.z; acc.hi.w += acc2.hi.w + b1.w;
    float4* H = reinterpret_cast<float4*>(out);
    H[(size_t)node * LANES * 2 + c * 2] = acc.lo;
    H[(size_t)node * LANES * 2 + c * 2 + 1] = acc.hi;
}

extern "C" void kernel_launch(void* const* d_in, const int* in_sizes, int n_in,
                              void* d_out, int out_size, void* d_ws, size_t ws_size,
                              hipStream_t stream) {
    const float* x  = (const float*)d_in[0];
    const int*   ei = (const int*)d_in[1];   // [2][E] int32
    const float* W0 = (const float*)d_in[2];
    const float* b0 = (const float*)d_in[3];
    const float* W1 = (const float*)d_in[4];
    const float* b1 = (const float*)d_in[5];
    const float* W2 = (const float*)d_in[6];
    const float* b2 = (const float*)d_in[7];
    float* out = (float*)d_out;

    const int n = in_sizes[0] / 128;   // 50000
    const int E = in_sizes[1] / 2;     // 800000
    const int NBLK = (n + 255) / 256;  // 196

    // workspace (~43 MB):
    // bp(12.8M u8x4) rank(0.8M) bsum/bpre offs dinv edata(3.2M)
    // A fp16(12.8M) B fp16(12.8M) Wh(80K)
    // partial (12.8M) ALIASES A (dead until gemm0).
    const int S = 51200;
    uint32* bp    = (uint32*)d_ws;
    uint8*  rank  = (uint8*)(bp + (size_t)NBINS * (NB / 4));
    int*    bsum  = (int*)(rank + E);
    int*    bpre  = bsum + 256;
    int*    offs  = bsum + S;
    float*  dinv  = (float*)(offs + S);
    uint32* edata = (uint32*)(dinv + S);
    __half* A     = (__half*)(edata + E);
    __half* B     = A + (size_t)n * 128;
    __half* Wh    = B + (size_t)n * 128;
    uint32* partial = (uint32*)A;   // NB*HW4 u32 = 12.8M = sizeof(A)

    // ---- one-time weight convert
    k_cvtw<<<40, 256, 0, stream>>>(W0, W1, W2, Wh);

    // ---- CSR build, zero global atomics
    k_hist<<<NB, 256, 0, stream>>>(ei, rank, partial, E);
    k_merge<<<NBLK, 256, 0, stream>>>(partial, bp, bsum, offs, dinv, n);
    k_scan_top<<<1, 256, 0, stream>>>(bsum, bpre, offs, NBLK, n);
    k_add<<<NBLK, 256, 0, stream>>>(offs, bpre, n);
    k_fill<<<(E + 255) / 256, 256, 0, stream>>>(ei, offs, bp, rank, dinv, edata, E);

    const int blocks64 = (n + 63) / 64;   // 782 (gemm0)
    const int blocks32 = (n + 31) / 32;   // 1563 (fused)

    // ---- P0 = x @ W0^T (fp32 in, fp16 out, inline convert)
    k_gemm0<8><<<blocks64, 256, 0, stream>>>(x, Wh, A, n);
    // ---- H0 = relu(gather(P0)+b0); P1 = H0 @ W1^T  (barrier-free fused)
    k_gg<8><<<blocks32, 128, 0, stream>>>(A, offs, edata, dinv, b0,
                                          Wh + 16384, B, n);
    // ---- H1 = relu(gather(P1)+b1); P2 = H1 @ W2^T  (fused, N=64)
    k_gg<4><<<blocks32, 128, 0, stream>>>(B, offs, edata, dinv, b1,
                                          Wh + 32768, A, n);
    // ---- out = gather(P2) + b2 (fp32)
    k_gather_out<<<(n * 8 + 255) / 256, 256, 0, stream>>>(
        A, offs, edata, dinv, b2, out, n);
}